// Round 10
// baseline (298.325 us; speedup 1.0000x reference)
//
#include <hip/hip_runtime.h>
#include <hip/hip_bf16.h>

// ---------------------------------------------------------------------------
// GCN 2-layer + edge dot logits, CSR-pull aggregation.
// agg[d] = dinv[d] * ( sum_{s in in(d)} hs[s] + hs[d] ) + b,  hs = (A@W)*dinv[row]
// Round 10: single-barrier GEMM (A-tile staged once in LDS; B streamed from
// L2/L1 -- W1/W2 are block-shared and cache-resident). Keeps r9's
// {GEMM1 || CSR-fill} fusion and persistent pull/logits kernels.
// ---------------------------------------------------------------------------

__global__ void cnt_k(const int* __restrict__ dst, int* __restrict__ cnt, int E) {
    int t = blockIdx.x * blockDim.x + threadIdx.x;
    int e = t * 4;
    if (e + 4 <= E) {
        int4 d4 = *reinterpret_cast<const int4*>(dst + e);
        atomicAdd(&cnt[d4.x], 1);
        atomicAdd(&cnt[d4.y], 1);
        atomicAdd(&cnt[d4.z], 1);
        atomicAdd(&cnt[d4.w], 1);
    } else {
        for (int i = e; i < E; i++) atomicAdd(&cnt[dst[i]], 1);
    }
}

__global__ void scan1_k(const int* __restrict__ cnt, int* __restrict__ incl,
                        int* __restrict__ bsum, int N) {
    __shared__ int sh[256];
    int i = blockIdx.x * 256 + threadIdx.x;
    int v = (i < N) ? cnt[i] : 0;
    sh[threadIdx.x] = v;
    __syncthreads();
#pragma unroll
    for (int off = 1; off < 256; off <<= 1) {
        int t = (threadIdx.x >= off) ? sh[threadIdx.x - off] : 0;
        __syncthreads();
        sh[threadIdx.x] += t;
        __syncthreads();
    }
    if (i < N) incl[i] = sh[threadIdx.x];
    if (threadIdx.x == 255) bsum[blockIdx.x] = sh[255];
}

// fused scan2+scan3: every block rescans bsum in LDS, then elementwise writeback.
__global__ __launch_bounds__(256) void scan23_k(const int* __restrict__ cnt,
                                                const int* __restrict__ incl,
                                                const int* __restrict__ bsum,
                                                int* __restrict__ rowptr,
                                                int* __restrict__ cursor,
                                                float* __restrict__ dinv,
                                                int N, int E, int NB) {
    __shared__ int sh[256];
    __shared__ int blockOff;
    int v = (threadIdx.x < NB) ? bsum[threadIdx.x] : 0;
    sh[threadIdx.x] = v;
    __syncthreads();
#pragma unroll
    for (int off = 1; off < 256; off <<= 1) {
        int t = (threadIdx.x >= off) ? sh[threadIdx.x - off] : 0;
        __syncthreads();
        sh[threadIdx.x] += t;
        __syncthreads();
    }
    if (threadIdx.x == blockIdx.x) blockOff = sh[threadIdx.x] - v;  // exclusive
    __syncthreads();
    int i = blockIdx.x * 256 + threadIdx.x;
    if (i < N) {
        int c = cnt[i];
        int excl = incl[i] - c + blockOff;
        rowptr[i] = excl;
        cursor[i] = excl;
        dinv[i] = rsqrtf(1.0f + (float)c);  // +1 self-loop
    }
    if (i == 0) rowptr[N] = E;
}

// ---------------------------------------------------------------------------
// Single-barrier GEMM body: stage A-tile (64x128) in LDS once, stream B from
// L2/L1. Out[M,BN] = (RELU? relu(A):A)[M,128] @ W[128,BN] * dscale[row].
// Thread (tx,ty): rows ty*4..+3, cols tx*TN..+TN-1. Per 4-k chunk:
// 4 b128 LDS A-reads (broadcast, 2-way = free) + 4*TN/4 float4 L2 B-loads
// + 16*TN FMA. No per-k-tile barriers.
// ---------------------------------------------------------------------------
template <int BN, bool RELU>
__device__ __forceinline__ void gemm_body(const float* __restrict__ A,
                                          const float* __restrict__ W,
                                          const float* __restrict__ dscale,
                                          float* __restrict__ Out, int M,
                                          float (*As)[132], int row0) {
    constexpr int K = 128;
    constexpr int TN = BN / 16;  // 8 (BN=128) or 4 (BN=64)
    const int tid = threadIdx.x;

    // ---- stage A tile: 64 rows x 128 = 2048 float4; 8 per thread ----
#pragma unroll
    for (int s = 0; s < 8; s++) {
        int flat = s * 256 + tid;
        int r = flat >> 5;             // 32 float4 per row
        int c4 = (flat & 31) << 2;
        float4 av = make_float4(0.f, 0.f, 0.f, 0.f);
        int gr = row0 + r;
        if (gr < M)
            av = *reinterpret_cast<const float4*>(A + (size_t)gr * K + c4);
        if (RELU) {
            av.x = fmaxf(av.x, 0.f); av.y = fmaxf(av.y, 0.f);
            av.z = fmaxf(av.z, 0.f); av.w = fmaxf(av.w, 0.f);
        }
        *reinterpret_cast<float4*>(&As[r][c4]) = av;
    }
    __syncthreads();  // the ONLY barrier

    const int tx = tid & 15, ty = tid >> 4;
    float acc[4][TN];
#pragma unroll
    for (int m = 0; m < 4; m++)
#pragma unroll
        for (int n = 0; n < TN; n++) acc[m][n] = 0.0f;

    const float* Wp = W + tx * TN;

#pragma unroll 4
    for (int k = 0; k < K; k += 4) {
        float a[4][4];
#pragma unroll
        for (int m = 0; m < 4; m++)
            *reinterpret_cast<float4*>(a[m]) =
                *reinterpret_cast<const float4*>(&As[ty * 4 + m][k]);
#pragma unroll
        for (int kk = 0; kk < 4; kk++) {
#pragma unroll
            for (int j4 = 0; j4 < TN / 4; j4++) {
                float4 bv = *reinterpret_cast<const float4*>(Wp + (size_t)(k + kk) * BN + j4 * 4);
#pragma unroll
                for (int m = 0; m < 4; m++) {
                    acc[m][j4 * 4 + 0] = fmaf(a[m][kk], bv.x, acc[m][j4 * 4 + 0]);
                    acc[m][j4 * 4 + 1] = fmaf(a[m][kk], bv.y, acc[m][j4 * 4 + 1]);
                    acc[m][j4 * 4 + 2] = fmaf(a[m][kk], bv.z, acc[m][j4 * 4 + 2]);
                    acc[m][j4 * 4 + 3] = fmaf(a[m][kk], bv.w, acc[m][j4 * 4 + 3]);
                }
            }
        }
    }

#pragma unroll
    for (int m = 0; m < 4; m++) {
        int gr = row0 + ty * 4 + m;
        if (gr < M) {
            float dv = dscale[gr];
#pragma unroll
            for (int j4 = 0; j4 < TN / 4; j4++) {
                float4 o = make_float4(acc[m][j4 * 4 + 0] * dv, acc[m][j4 * 4 + 1] * dv,
                                       acc[m][j4 * 4 + 2] * dv, acc[m][j4 * 4 + 3] * dv);
                *reinterpret_cast<float4*>(Out + (size_t)gr * BN + tx * TN + j4 * 4) = o;
            }
        }
    }
}

// ---------------------------------------------------------------------------
// FUSED: blocks [0,gemmBlocks) = GEMM1 (x@W1*dinv); rest = CSR fill (int2).
// Both depend only on scan23; independent -> overlap in one launch.
// ---------------------------------------------------------------------------
__global__ __launch_bounds__(256) void gemm1_fill_k(const float* __restrict__ A,
                                                    const float* __restrict__ W,
                                                    const float* __restrict__ dscale,
                                                    float* __restrict__ Out, int M,
                                                    const int* __restrict__ src,
                                                    const int* __restrict__ dst,
                                                    int* __restrict__ cursor,
                                                    int2* __restrict__ col2, int E,
                                                    int gemmBlocks) {
    __shared__ float As[64][132];
    if ((int)blockIdx.x >= gemmBlocks) {
        int t = ((int)blockIdx.x - gemmBlocks) * 256 + threadIdx.x;
        int e = t * 4;
        if (e + 4 <= E) {
            int4 s4 = *reinterpret_cast<const int4*>(src + e);
            int4 d4 = *reinterpret_cast<const int4*>(dst + e);
            int p0 = atomicAdd(&cursor[d4.x], 1);
            col2[p0] = make_int2(s4.x, e + 0);
            int p1 = atomicAdd(&cursor[d4.y], 1);
            col2[p1] = make_int2(s4.y, e + 1);
            int p2 = atomicAdd(&cursor[d4.z], 1);
            col2[p2] = make_int2(s4.z, e + 2);
            int p3 = atomicAdd(&cursor[d4.w], 1);
            col2[p3] = make_int2(s4.w, e + 3);
        } else {
            for (int i = e; i < E; i++) {
                int pos = atomicAdd(&cursor[dst[i]], 1);
                col2[pos] = make_int2(src[i], i);
            }
        }
        return;
    }
    gemm_body<128, false>(A, W, dscale, Out, M, As, (int)blockIdx.x * 64);
}

__global__ __launch_bounds__(256) void gemm2_k(const float* __restrict__ A,
                                               const float* __restrict__ W,
                                               const float* __restrict__ dscale,
                                               float* __restrict__ Out, int M) {
    __shared__ float As[64][132];
    gemm_body<64, true>(A, W, dscale, Out, M, As, (int)blockIdx.x * 64);
}

// ---------------------------------------------------------------------------
// pull128: persistent, one wave per node per iteration; 2 slots x 32 lanes.
// ---------------------------------------------------------------------------
__global__ __launch_bounds__(256) void pull128_k(const int* __restrict__ rowptr,
                                                 const int2* __restrict__ col2,
                                                 const float4* __restrict__ hs4,
                                                 const float* __restrict__ dinv,
                                                 const float4* __restrict__ bias4,
                                                 float4* __restrict__ out4, int N) {
    int wid = (int)((blockIdx.x * blockDim.x + threadIdx.x) >> 6);
    int nw = (int)((gridDim.x * blockDim.x) >> 6);
    int lane = threadIdx.x & 63;
    int q = lane & 31, slot = lane >> 5;

    for (int v = wid; v < N; v += nw) {
        int p0 = rowptr[v], p1 = rowptr[v + 1];

        float4 acc = make_float4(0.f, 0.f, 0.f, 0.f);
        if (slot == 0) acc = hs4[(size_t)v * 32 + q];  // self row

        int p = p0;
        for (; p + 8 <= p1; p += 8) {
            int ia = col2[p + slot].x, ib = col2[p + 2 + slot].x;
            int ic = col2[p + 4 + slot].x, id = col2[p + 6 + slot].x;
            float4 a = hs4[(size_t)ia * 32 + q];
            float4 b = hs4[(size_t)ib * 32 + q];
            float4 c = hs4[(size_t)ic * 32 + q];
            float4 d = hs4[(size_t)id * 32 + q];
            acc.x += (a.x + b.x) + (c.x + d.x);
            acc.y += (a.y + b.y) + (c.y + d.y);
            acc.z += (a.z + b.z) + (c.z + d.z);
            acc.w += (a.w + b.w) + (c.w + d.w);
        }
        for (; p + 2 <= p1; p += 2) {
            int ia = col2[p + slot].x;
            float4 a = hs4[(size_t)ia * 32 + q];
            acc.x += a.x; acc.y += a.y; acc.z += a.z; acc.w += a.w;
        }
        if (p < p1 && slot == 0) {
            float4 a = hs4[(size_t)col2[p].x * 32 + q];
            acc.x += a.x; acc.y += a.y; acc.z += a.z; acc.w += a.w;
        }

        acc.x += __shfl_xor(acc.x, 32);
        acc.y += __shfl_xor(acc.y, 32);
        acc.z += __shfl_xor(acc.z, 32);
        acc.w += __shfl_xor(acc.w, 32);

        if (slot == 0) {
            float dv = dinv[v];
            float4 bv = bias4[q];
            out4[(size_t)v * 32 + q] = make_float4(fmaf(acc.x, dv, bv.x), fmaf(acc.y, dv, bv.y),
                                                   fmaf(acc.z, dv, bv.z), fmaf(acc.w, dv, bv.w));
        }
    }
}

// ---------------------------------------------------------------------------
// pull64: persistent, 4 slots x 16 lanes.
// ---------------------------------------------------------------------------
__global__ __launch_bounds__(256) void pull64_k(const int* __restrict__ rowptr,
                                                const int2* __restrict__ col2,
                                                const float4* __restrict__ hs4,
                                                const float* __restrict__ dinv,
                                                const float4* __restrict__ bias4,
                                                float4* __restrict__ out4, int N) {
    int wid = (int)((blockIdx.x * blockDim.x + threadIdx.x) >> 6);
    int nw = (int)((gridDim.x * blockDim.x) >> 6);
    int lane = threadIdx.x & 63;
    int q = lane & 15, slot = lane >> 4;

    for (int v = wid; v < N; v += nw) {
        int p0 = rowptr[v], p1 = rowptr[v + 1];

        float4 acc = make_float4(0.f, 0.f, 0.f, 0.f);
        if (slot == 0) acc = hs4[(size_t)v * 16 + q];  // self row

        int p = p0;
        for (; p + 8 <= p1; p += 8) {
            int ia = col2[p + slot].x, ib = col2[p + 4 + slot].x;
            float4 a = hs4[(size_t)ia * 16 + q];
            float4 b = hs4[(size_t)ib * 16 + q];
            acc.x += a.x + b.x; acc.y += a.y + b.y;
            acc.z += a.z + b.z; acc.w += a.w + b.w;
        }
        for (; p + 4 <= p1; p += 4) {
            float4 a = hs4[(size_t)col2[p + slot].x * 16 + q];
            acc.x += a.x; acc.y += a.y; acc.z += a.z; acc.w += a.w;
        }
        int rem = p1 - p;  // 0..3
        if (slot < rem) {
            float4 a = hs4[(size_t)col2[p + slot].x * 16 + q];
            acc.x += a.x; acc.y += a.y; acc.z += a.z; acc.w += a.w;
        }

#pragma unroll
        for (int off = 16; off <= 32; off <<= 1) {
            acc.x += __shfl_xor(acc.x, off);
            acc.y += __shfl_xor(acc.y, off);
            acc.z += __shfl_xor(acc.z, off);
            acc.w += __shfl_xor(acc.w, off);
        }

        if (slot == 0) {
            float dv = dinv[v];
            float4 bv = bias4[q];
            out4[(size_t)v * 16 + q] = make_float4(fmaf(acc.x, dv, bv.x), fmaf(acc.y, dv, bv.y),
                                                   fmaf(acc.z, dv, bv.z), fmaf(acc.w, dv, bv.w));
        }
    }
}

// ---------------------------------------------------------------------------
// logits: persistent CSR; dst row wave-resident, src rows gathered.
// ---------------------------------------------------------------------------
__global__ __launch_bounds__(256) void logits_csr_k(const int* __restrict__ rowptr,
                                                    const int2* __restrict__ col2,
                                                    const float4* __restrict__ h4,
                                                    float* __restrict__ out, int N) {
    int wid = (int)((blockIdx.x * blockDim.x + threadIdx.x) >> 6);
    int nw = (int)((gridDim.x * blockDim.x) >> 6);
    int lane = threadIdx.x & 63;
    int q = lane & 15, slot = lane >> 4;

    for (int v = wid; v < N; v += nw) {
        int p0 = rowptr[v], p1 = rowptr[v + 1];
        if (p0 == p1) continue;

        float4 rd = h4[(size_t)v * 16 + q];  // dst row

        int p = p0;
        for (; p + 8 <= p1; p += 8) {
            int2 ca = col2[p + slot], cb = col2[p + 4 + slot];
            float4 ra = h4[(size_t)ca.x * 16 + q];
            float4 rb = h4[(size_t)cb.x * 16 + q];
            float t0 = rd.x * ra.x + rd.y * ra.y + rd.z * ra.z + rd.w * ra.w;
            float t1 = rd.x * rb.x + rd.y * rb.y + rd.z * rb.z + rd.w * rb.w;
#pragma unroll
            for (int off = 1; off < 16; off <<= 1) {
                t0 += __shfl_xor(t0, off);
                t1 += __shfl_xor(t1, off);
            }
            if (q == 0) { out[ca.y] = t0; out[cb.y] = t1; }
        }
        for (; p + 4 <= p1; p += 4) {
            int2 ca = col2[p + slot];
            float4 ra = h4[(size_t)ca.x * 16 + q];
            float t0 = rd.x * ra.x + rd.y * ra.y + rd.z * ra.z + rd.w * ra.w;
#pragma unroll
            for (int off = 1; off < 16; off <<= 1) t0 += __shfl_xor(t0, off);
            if (q == 0) out[ca.y] = t0;
        }
        int rem = p1 - p;  // 0..3
        if (slot < rem) {
            int2 ca = col2[p + slot];
            float4 ra = h4[(size_t)ca.x * 16 + q];
            float t0 = rd.x * ra.x + rd.y * ra.y + rd.z * ra.z + rd.w * ra.w;
#pragma unroll
            for (int off = 1; off < 16; off <<= 1) t0 += __shfl_xor(t0, off);
            if (q == 0) out[ca.y] = t0;
        }
    }
}

extern "C" void kernel_launch(void* const* d_in, const int* in_sizes, int n_in,
                              void* d_out, int out_size, void* d_ws, size_t ws_size,
                              hipStream_t stream) {
    const float* x  = (const float*)d_in[0];
    const int* ei   = (const int*)d_in[1];   // int32 (harness converts ints)
    const float* W1 = (const float*)d_in[2];
    const float* b1 = (const float*)d_in[3];
    const float* W2 = (const float*)d_in[4];
    const float* b2 = (const float*)d_in[5];
    float* out = (float*)d_out;

    const int N = in_sizes[0] / 128;   // 50000
    const int E = in_sizes[1] / 2;     // 800000
    const int* src = ei;
    const int* dst = ei + E;

    // ---- workspace ----
    // floats: dinv[50176] | bufA[N*128] | bufB[N*128]
    // ints:   cnt[N] | incl[N] | rowptr[N+2] | cursor[N] | bsum[256] | col2[E] (int2)
    float* ws   = (float*)d_ws;
    float* dinv = ws;
    float* bufA = ws + 50176;
    float* bufB = bufA + (size_t)N * 128;
    float* hs1  = bufA;
    float* agg1 = bufB;
    float* g2s  = bufA;
    float* agg2 = bufA + (size_t)N * 64;

    int* ibase  = (int*)(bufB + (size_t)N * 128);
    int* cnt    = ibase;
    int* incl   = cnt + N;
    int* rowptr = incl + N;
    int* cursor = rowptr + (N + 2);    // keeps later offsets 8B-aligned
    int* bsum   = cursor + N;
    int2* col2  = (int2*)(bsum + 256);

    const int B = 256;
    const int NB = (N + 255) / 256;   // 196
    const unsigned persBlocks = 2048;

    // ---- CSR count + scan ----
    hipMemsetAsync(cnt, 0, (size_t)N * sizeof(int), stream);
    cnt_k<<<(E / 4 + B - 1) / B, B, 0, stream>>>(dst, cnt, E);
    scan1_k<<<NB, 256, 0, stream>>>(cnt, incl, bsum, N);
    scan23_k<<<NB, 256, 0, stream>>>(cnt, incl, bsum, rowptr, cursor, dinv, N, E, NB);

    // ---- fused: GEMM1 (hs1 = x@W1*dinv, single-barrier) + CSR fill (col2) ----
    {
        int gemmBlocks = (N + 63) / 64;              // 782
        int fillBlocks = (E / 4 + B - 1) / B;        // 782
        gemm1_fill_k<<<gemmBlocks + fillBlocks, 256, 0, stream>>>(
            x, W1, dinv, hs1, N, src, dst, cursor, col2, E, gemmBlocks);
    }

    // ---- layer 1 pull ----
    pull128_k<<<persBlocks, 256, 0, stream>>>(rowptr, col2, (const float4*)hs1, dinv,
                                              (const float4*)b1, (float4*)agg1, N);

    // ---- layer 2 ----
    gemm2_k<<<(N + 63) / 64, 256, 0, stream>>>(agg1, W2, dinv, g2s, N);
    pull64_k<<<persBlocks, 256, 0, stream>>>(rowptr, col2, (const float4*)g2s, dinv,
                                             (const float4*)b2, (float4*)agg2, N);

    // ---- edge logits ----
    logits_csr_k<<<persBlocks, 256, 0, stream>>>(rowptr, col2, (const float4*)agg2, out, N);
}

// Round 11
// 257.791 us; speedup vs baseline: 1.1572x; 1.1572x over previous
//
#include <hip/hip_runtime.h>
#include <hip/hip_bf16.h>

// ---------------------------------------------------------------------------
// GCN 2-layer + edge dot logits, CSR-pull aggregation.
// agg[d] = dinv[d] * ( sum_{s in in(d)} hs[s] + hs[d] ) + b,  hs = (A@W)*dinv[row]
// Round 11: r9 structure; GEMM reworked for parallelism: BM=32 (2x blocks,
// ~6/CU co-resident hides barriers), conflict-free column map {tx*4, 64+tx*4}
// (2-way = free), k-major As with pad 4. Keeps {GEMM1 || CSR-fill} fusion and
// persistent pull/logits. Pulls are at the ~3.6 TB/s L2-fill floor - untouched.
// ---------------------------------------------------------------------------

__global__ void cnt_k(const int* __restrict__ dst, int* __restrict__ cnt, int E) {
    int t = blockIdx.x * blockDim.x + threadIdx.x;
    int e = t * 4;
    if (e + 4 <= E) {
        int4 d4 = *reinterpret_cast<const int4*>(dst + e);
        atomicAdd(&cnt[d4.x], 1);
        atomicAdd(&cnt[d4.y], 1);
        atomicAdd(&cnt[d4.z], 1);
        atomicAdd(&cnt[d4.w], 1);
    } else {
        for (int i = e; i < E; i++) atomicAdd(&cnt[dst[i]], 1);
    }
}

__global__ void scan1_k(const int* __restrict__ cnt, int* __restrict__ incl,
                        int* __restrict__ bsum, int N) {
    __shared__ int sh[256];
    int i = blockIdx.x * 256 + threadIdx.x;
    int v = (i < N) ? cnt[i] : 0;
    sh[threadIdx.x] = v;
    __syncthreads();
#pragma unroll
    for (int off = 1; off < 256; off <<= 1) {
        int t = (threadIdx.x >= off) ? sh[threadIdx.x - off] : 0;
        __syncthreads();
        sh[threadIdx.x] += t;
        __syncthreads();
    }
    if (i < N) incl[i] = sh[threadIdx.x];
    if (threadIdx.x == 255) bsum[blockIdx.x] = sh[255];
}

// fused scan2+scan3: every block rescans bsum in LDS, then elementwise writeback.
__global__ __launch_bounds__(256) void scan23_k(const int* __restrict__ cnt,
                                                const int* __restrict__ incl,
                                                const int* __restrict__ bsum,
                                                int* __restrict__ rowptr,
                                                int* __restrict__ cursor,
                                                float* __restrict__ dinv,
                                                int N, int E, int NB) {
    __shared__ int sh[256];
    __shared__ int blockOff;
    int v = (threadIdx.x < NB) ? bsum[threadIdx.x] : 0;
    sh[threadIdx.x] = v;
    __syncthreads();
#pragma unroll
    for (int off = 1; off < 256; off <<= 1) {
        int t = (threadIdx.x >= off) ? sh[threadIdx.x - off] : 0;
        __syncthreads();
        sh[threadIdx.x] += t;
        __syncthreads();
    }
    if (threadIdx.x == blockIdx.x) blockOff = sh[threadIdx.x] - v;  // exclusive
    __syncthreads();
    int i = blockIdx.x * 256 + threadIdx.x;
    if (i < N) {
        int c = cnt[i];
        int excl = incl[i] - c + blockOff;
        rowptr[i] = excl;
        cursor[i] = excl;
        dinv[i] = rsqrtf(1.0f + (float)c);  // +1 self-loop
    }
    if (i == 0) rowptr[N] = E;
}

// ---------------------------------------------------------------------------
// GEMM body, BM=32, BK=16, 256 threads. Thread (tx,ty): rows ty*2..+1,
// cols {tx*4..+3} and (BN=128) {64+tx*4..+3}  -> Bs reads 2-way (free).
// As k-major, pad 4 -> stores/reads 2-way/broadcast (free).
// ---------------------------------------------------------------------------
template <int BN, bool RELU>
__device__ __forceinline__ void gemm_body32(const float* __restrict__ A,
                                            const float* __restrict__ W,
                                            const float* __restrict__ dscale,
                                            float* __restrict__ Out, int M,
                                            int row0, float (*As)[36],
                                            float (*Bs)[BN]) {
    constexpr int K = 128, BK = 16;
    constexpr int TN = BN / 16;  // 8 (BN=128) or 4 (BN=64)
    const int tid = threadIdx.x;
    const int tx = tid & 15, ty = tid >> 4;

    float acc[2][TN];
#pragma unroll
    for (int m = 0; m < 2; m++)
#pragma unroll
        for (int n = 0; n < TN; n++) acc[m][n] = 0.0f;

    for (int kt = 0; kt < K; kt += BK) {
        // --- stage A (32x16, k-major): threads 0..127, one float4 each ---
        if (tid < 128) {
            int r = tid >> 2;            // 0..31
            int kq = (tid & 3) * 4;      // 0,4,8,12
            float4 av = make_float4(0.f, 0.f, 0.f, 0.f);
            int gr = row0 + r;
            if (gr < M)
                av = *reinterpret_cast<const float4*>(A + (size_t)gr * K + kt + kq);
            if (RELU) {
                av.x = fmaxf(av.x, 0.f); av.y = fmaxf(av.y, 0.f);
                av.z = fmaxf(av.z, 0.f); av.w = fmaxf(av.w, 0.f);
            }
            As[kq + 0][r] = av.x; As[kq + 1][r] = av.y;
            As[kq + 2][r] = av.z; As[kq + 3][r] = av.w;
        }
        // --- stage B (16xBN): (BK*BN)/1024 float4 per thread ---
#pragma unroll
        for (int s = 0; s < (BK * BN) / (256 * 4); s++) {
            int f = s * 256 + tid;
            int brow = f / (BN / 4);
            int bcol = (f % (BN / 4)) * 4;
            float4 bv = *reinterpret_cast<const float4*>(W + (size_t)(kt + brow) * BN + bcol);
            *reinterpret_cast<float4*>(&Bs[brow][bcol]) = bv;
        }
        __syncthreads();

#pragma unroll
        for (int k = 0; k < BK; k++) {
            float2 a2 = *reinterpret_cast<const float2*>(&As[k][ty * 2]);
            float a[2] = {a2.x, a2.y};
            float b[TN];
            float4 b0 = *reinterpret_cast<const float4*>(&Bs[k][tx * 4]);
            b[0] = b0.x; b[1] = b0.y; b[2] = b0.z; b[3] = b0.w;
            if (TN == 8) {
                float4 b1 = *reinterpret_cast<const float4*>(&Bs[k][64 + tx * 4]);
                b[4] = b1.x; b[5] = b1.y; b[6] = b1.z; b[7] = b1.w;
            }
#pragma unroll
            for (int m = 0; m < 2; m++)
#pragma unroll
                for (int n = 0; n < TN; n++) acc[m][n] = fmaf(a[m], b[n], acc[m][n]);
        }
        __syncthreads();
    }

#pragma unroll
    for (int m = 0; m < 2; m++) {
        int gr = row0 + ty * 2 + m;
        if (gr < M) {
            float dv = dscale[gr];
            float4 o0 = make_float4(acc[m][0] * dv, acc[m][1] * dv,
                                    acc[m][2] * dv, acc[m][3] * dv);
            *reinterpret_cast<float4*>(Out + (size_t)gr * BN + tx * 4) = o0;
            if (TN == 8) {
                float4 o1 = make_float4(acc[m][4] * dv, acc[m][5] * dv,
                                        acc[m][6] * dv, acc[m][7] * dv);
                *reinterpret_cast<float4*>(Out + (size_t)gr * BN + 64 + tx * 4) = o1;
            }
        }
    }
}

// ---------------------------------------------------------------------------
// FUSED: blocks [0,gemmBlocks) = GEMM1 (x@W1*dinv); rest = CSR fill (int2).
// Both depend only on scan23; independent -> overlap in one launch.
// ---------------------------------------------------------------------------
__global__ __launch_bounds__(256) void gemm1_fill_k(const float* __restrict__ A,
                                                    const float* __restrict__ W,
                                                    const float* __restrict__ dscale,
                                                    float* __restrict__ Out, int M,
                                                    const int* __restrict__ src,
                                                    const int* __restrict__ dst,
                                                    int* __restrict__ cursor,
                                                    int2* __restrict__ col2, int E,
                                                    int gemmBlocks) {
    __shared__ float As[16][36];
    __shared__ float Bs[16][128];
    if ((int)blockIdx.x >= gemmBlocks) {
        int t = ((int)blockIdx.x - gemmBlocks) * 256 + threadIdx.x;
        int e = t * 4;
        if (e + 4 <= E) {
            int4 s4 = *reinterpret_cast<const int4*>(src + e);
            int4 d4 = *reinterpret_cast<const int4*>(dst + e);
            int p0 = atomicAdd(&cursor[d4.x], 1);
            col2[p0] = make_int2(s4.x, e + 0);
            int p1 = atomicAdd(&cursor[d4.y], 1);
            col2[p1] = make_int2(s4.y, e + 1);
            int p2 = atomicAdd(&cursor[d4.z], 1);
            col2[p2] = make_int2(s4.z, e + 2);
            int p3 = atomicAdd(&cursor[d4.w], 1);
            col2[p3] = make_int2(s4.w, e + 3);
        } else {
            for (int i = e; i < E; i++) {
                int pos = atomicAdd(&cursor[dst[i]], 1);
                col2[pos] = make_int2(src[i], i);
            }
        }
        return;
    }
    gemm_body32<128, false>(A, W, dscale, Out, M, (int)blockIdx.x * 32, As, Bs);
}

__global__ __launch_bounds__(256) void gemm2_k(const float* __restrict__ A,
                                               const float* __restrict__ W,
                                               const float* __restrict__ dscale,
                                               float* __restrict__ Out, int M) {
    __shared__ float As[16][36];
    __shared__ float Bs[16][64];
    gemm_body32<64, true>(A, W, dscale, Out, M, (int)blockIdx.x * 32, As, Bs);
}

// ---------------------------------------------------------------------------
// pull128: persistent, one wave per node per iteration; 2 slots x 32 lanes.
// ---------------------------------------------------------------------------
__global__ __launch_bounds__(256) void pull128_k(const int* __restrict__ rowptr,
                                                 const int2* __restrict__ col2,
                                                 const float4* __restrict__ hs4,
                                                 const float* __restrict__ dinv,
                                                 const float4* __restrict__ bias4,
                                                 float4* __restrict__ out4, int N) {
    int wid = (int)((blockIdx.x * blockDim.x + threadIdx.x) >> 6);
    int nw = (int)((gridDim.x * blockDim.x) >> 6);
    int lane = threadIdx.x & 63;
    int q = lane & 31, slot = lane >> 5;

    for (int v = wid; v < N; v += nw) {
        int p0 = rowptr[v], p1 = rowptr[v + 1];

        float4 acc = make_float4(0.f, 0.f, 0.f, 0.f);
        if (slot == 0) acc = hs4[(size_t)v * 32 + q];  // self row

        int p = p0;
        for (; p + 8 <= p1; p += 8) {
            int ia = col2[p + slot].x, ib = col2[p + 2 + slot].x;
            int ic = col2[p + 4 + slot].x, id = col2[p + 6 + slot].x;
            float4 a = hs4[(size_t)ia * 32 + q];
            float4 b = hs4[(size_t)ib * 32 + q];
            float4 c = hs4[(size_t)ic * 32 + q];
            float4 d = hs4[(size_t)id * 32 + q];
            acc.x += (a.x + b.x) + (c.x + d.x);
            acc.y += (a.y + b.y) + (c.y + d.y);
            acc.z += (a.z + b.z) + (c.z + d.z);
            acc.w += (a.w + b.w) + (c.w + d.w);
        }
        for (; p + 2 <= p1; p += 2) {
            int ia = col2[p + slot].x;
            float4 a = hs4[(size_t)ia * 32 + q];
            acc.x += a.x; acc.y += a.y; acc.z += a.z; acc.w += a.w;
        }
        if (p < p1 && slot == 0) {
            float4 a = hs4[(size_t)col2[p].x * 32 + q];
            acc.x += a.x; acc.y += a.y; acc.z += a.z; acc.w += a.w;
        }

        acc.x += __shfl_xor(acc.x, 32);
        acc.y += __shfl_xor(acc.y, 32);
        acc.z += __shfl_xor(acc.z, 32);
        acc.w += __shfl_xor(acc.w, 32);

        if (slot == 0) {
            float dv = dinv[v];
            float4 bv = bias4[q];
            out4[(size_t)v * 32 + q] = make_float4(fmaf(acc.x, dv, bv.x), fmaf(acc.y, dv, bv.y),
                                                   fmaf(acc.z, dv, bv.z), fmaf(acc.w, dv, bv.w));
        }
    }
}

// ---------------------------------------------------------------------------
// pull64: persistent, 4 slots x 16 lanes.
// ---------------------------------------------------------------------------
__global__ __launch_bounds__(256) void pull64_k(const int* __restrict__ rowptr,
                                                const int2* __restrict__ col2,
                                                const float4* __restrict__ hs4,
                                                const float* __restrict__ dinv,
                                                const float4* __restrict__ bias4,
                                                float4* __restrict__ out4, int N) {
    int wid = (int)((blockIdx.x * blockDim.x + threadIdx.x) >> 6);
    int nw = (int)((gridDim.x * blockDim.x) >> 6);
    int lane = threadIdx.x & 63;
    int q = lane & 15, slot = lane >> 4;

    for (int v = wid; v < N; v += nw) {
        int p0 = rowptr[v], p1 = rowptr[v + 1];

        float4 acc = make_float4(0.f, 0.f, 0.f, 0.f);
        if (slot == 0) acc = hs4[(size_t)v * 16 + q];  // self row

        int p = p0;
        for (; p + 8 <= p1; p += 8) {
            int ia = col2[p + slot].x, ib = col2[p + 4 + slot].x;
            float4 a = hs4[(size_t)ia * 16 + q];
            float4 b = hs4[(size_t)ib * 16 + q];
            acc.x += a.x + b.x; acc.y += a.y + b.y;
            acc.z += a.z + b.z; acc.w += a.w + b.w;
        }
        for (; p + 4 <= p1; p += 4) {
            float4 a = hs4[(size_t)col2[p + slot].x * 16 + q];
            acc.x += a.x; acc.y += a.y; acc.z += a.z; acc.w += a.w;
        }
        int rem = p1 - p;  // 0..3
        if (slot < rem) {
            float4 a = hs4[(size_t)col2[p + slot].x * 16 + q];
            acc.x += a.x; acc.y += a.y; acc.z += a.z; acc.w += a.w;
        }

#pragma unroll
        for (int off = 16; off <= 32; off <<= 1) {
            acc.x += __shfl_xor(acc.x, off);
            acc.y += __shfl_xor(acc.y, off);
            acc.z += __shfl_xor(acc.z, off);
            acc.w += __shfl_xor(acc.w, off);
        }

        if (slot == 0) {
            float dv = dinv[v];
            float4 bv = bias4[q];
            out4[(size_t)v * 16 + q] = make_float4(fmaf(acc.x, dv, bv.x), fmaf(acc.y, dv, bv.y),
                                                   fmaf(acc.z, dv, bv.z), fmaf(acc.w, dv, bv.w));
        }
    }
}

// ---------------------------------------------------------------------------
// logits: persistent CSR; dst row wave-resident, src rows gathered.
// ---------------------------------------------------------------------------
__global__ __launch_bounds__(256) void logits_csr_k(const int* __restrict__ rowptr,
                                                    const int2* __restrict__ col2,
                                                    const float4* __restrict__ h4,
                                                    float* __restrict__ out, int N) {
    int wid = (int)((blockIdx.x * blockDim.x + threadIdx.x) >> 6);
    int nw = (int)((gridDim.x * blockDim.x) >> 6);
    int lane = threadIdx.x & 63;
    int q = lane & 15, slot = lane >> 4;

    for (int v = wid; v < N; v += nw) {
        int p0 = rowptr[v], p1 = rowptr[v + 1];
        if (p0 == p1) continue;

        float4 rd = h4[(size_t)v * 16 + q];  // dst row

        int p = p0;
        for (; p + 8 <= p1; p += 8) {
            int2 ca = col2[p + slot], cb = col2[p + 4 + slot];
            float4 ra = h4[(size_t)ca.x * 16 + q];
            float4 rb = h4[(size_t)cb.x * 16 + q];
            float t0 = rd.x * ra.x + rd.y * ra.y + rd.z * ra.z + rd.w * ra.w;
            float t1 = rd.x * rb.x + rd.y * rb.y + rd.z * rb.z + rd.w * rb.w;
#pragma unroll
            for (int off = 1; off < 16; off <<= 1) {
                t0 += __shfl_xor(t0, off);
                t1 += __shfl_xor(t1, off);
            }
            if (q == 0) { out[ca.y] = t0; out[cb.y] = t1; }
        }
        for (; p + 4 <= p1; p += 4) {
            int2 ca = col2[p + slot];
            float4 ra = h4[(size_t)ca.x * 16 + q];
            float t0 = rd.x * ra.x + rd.y * ra.y + rd.z * ra.z + rd.w * ra.w;
#pragma unroll
            for (int off = 1; off < 16; off <<= 1) t0 += __shfl_xor(t0, off);
            if (q == 0) out[ca.y] = t0;
        }
        int rem = p1 - p;  // 0..3
        if (slot < rem) {
            int2 ca = col2[p + slot];
            float4 ra = h4[(size_t)ca.x * 16 + q];
            float t0 = rd.x * ra.x + rd.y * ra.y + rd.z * ra.z + rd.w * ra.w;
#pragma unroll
            for (int off = 1; off < 16; off <<= 1) t0 += __shfl_xor(t0, off);
            if (q == 0) out[ca.y] = t0;
        }
    }
}

extern "C" void kernel_launch(void* const* d_in, const int* in_sizes, int n_in,
                              void* d_out, int out_size, void* d_ws, size_t ws_size,
                              hipStream_t stream) {
    const float* x  = (const float*)d_in[0];
    const int* ei   = (const int*)d_in[1];   // int32 (harness converts ints)
    const float* W1 = (const float*)d_in[2];
    const float* b1 = (const float*)d_in[3];
    const float* W2 = (const float*)d_in[4];
    const float* b2 = (const float*)d_in[5];
    float* out = (float*)d_out;

    const int N = in_sizes[0] / 128;   // 50000
    const int E = in_sizes[1] / 2;     // 800000
    const int* src = ei;
    const int* dst = ei + E;

    // ---- workspace ----
    // floats: dinv[50176] | bufA[N*128] | bufB[N*128]
    // ints:   cnt[N] | incl[N] | rowptr[N+2] | cursor[N] | bsum[256] | col2[E] (int2)
    float* ws   = (float*)d_ws;
    float* dinv = ws;
    float* bufA = ws + 50176;
    float* bufB = bufA + (size_t)N * 128;
    float* hs1  = bufA;
    float* agg1 = bufB;
    float* g2s  = bufA;
    float* agg2 = bufA + (size_t)N * 64;

    int* ibase  = (int*)(bufB + (size_t)N * 128);
    int* cnt    = ibase;
    int* incl   = cnt + N;
    int* rowptr = incl + N;
    int* cursor = rowptr + (N + 2);    // keeps later offsets 8B-aligned
    int* bsum   = cursor + N;
    int2* col2  = (int2*)(bsum + 256);

    const int B = 256;
    const int NB = (N + 255) / 256;   // 196
    const unsigned persBlocks = 2048;

    // ---- CSR count + scan ----
    hipMemsetAsync(cnt, 0, (size_t)N * sizeof(int), stream);
    cnt_k<<<(E / 4 + B - 1) / B, B, 0, stream>>>(dst, cnt, E);
    scan1_k<<<NB, 256, 0, stream>>>(cnt, incl, bsum, N);
    scan23_k<<<NB, 256, 0, stream>>>(cnt, incl, bsum, rowptr, cursor, dinv, N, E, NB);

    // ---- fused: GEMM1 (hs1 = x@W1*dinv, BM=32) + CSR fill (col2) ----
    {
        int gemmBlocks = (N + 31) / 32;              // 1563
        int fillBlocks = (E / 4 + B - 1) / B;        // 782
        gemm1_fill_k<<<gemmBlocks + fillBlocks, 256, 0, stream>>>(
            x, W1, dinv, hs1, N, src, dst, cursor, col2, E, gemmBlocks);
    }

    // ---- layer 1 pull ----
    pull128_k<<<persBlocks, 256, 0, stream>>>(rowptr, col2, (const float4*)hs1, dinv,
                                              (const float4*)b1, (float4*)agg1, N);

    // ---- layer 2 ----
    gemm2_k<<<(N + 31) / 32, 256, 0, stream>>>(agg1, W2, dinv, g2s, N);
    pull64_k<<<persBlocks, 256, 0, stream>>>(rowptr, col2, (const float4*)g2s, dinv,
                                             (const float4*)b2, (float4*)agg2, N);

    // ---- edge logits ----
    logits_csr_k<<<persBlocks, 256, 0, stream>>>(rowptr, col2, (const float4*)agg2, out, N);
}